// Round 9
// baseline (202.342 us; speedup 1.0000x reference)
//
#include <hip/hip_runtime.h>
#include <stdint.h>

#define NDIM 8192
#define DDIM 256
#define WCAP 256   // per-wave candidate capacity
#define MAXK 64

typedef float v4f __attribute__((ext_vector_type(4)));
typedef unsigned long long u64;

// Map float bits to an unsigned key with the same total order.
__device__ inline uint32_t f2key(float f) {
    uint32_t u = __float_as_uint(f);
    return (u & 0x80000000u) ? ~u : (u | 0x80000000u);
}

// One WAVE per row. No __syncthreads anywhere: all collection/selection is
// wave-synchronous (ballot + prefix-popc), so no vmcnt(0) barrier drains —
// each wave's 32 row loads pipeline freely under its own scan/select work,
// and the CU's 12 resident waves stream A independently (no lockstep).
__global__ __launch_bounds__(256, 3) void topk_agg_wave(
    const float* __restrict__ A, const float* __restrict__ X,
    const float* __restrict__ alpha_p, const int* __restrict__ k_p,
    float* __restrict__ out)
{
    const int tid  = threadIdx.x;
    const int lane = tid & 63;
    const int wid  = tid >> 6;
    const int row  = blockIdx.x * 4 + wid;

    // Wave-private LDS regions — disjoint per wave, never cross-wave shared.
    __shared__ u64 cand_s[4][WCAP];
    __shared__ int sel_s[4][MAXK];
    u64* cand = cand_s[wid];
    int* sel  = sel_s[wid];

    int k = *k_p;
    if (k > MAXK) k = MAXK;            // defensive clamp (k==32 here)
    const float alpha = *alpha_p;

    // Residual: lane owns cols 4*lane..4*lane+3 (coalesced float4).
    const v4f xres =
        *reinterpret_cast<const v4f*>(X + (size_t)row * DDIM + 4 * lane);

    // Whole row register-resident: 32 independent NT float4 loads.
    // Consumption order == issue order -> compiler emits progressive
    // s_waitcnt vmcnt(N), overlapping scan with in-flight loads.
    const v4f* p = reinterpret_cast<const v4f*>(A + (size_t)row * NDIM);
    v4f r[32];
    #pragma unroll
    for (int i = 0; i < 32; ++i)
        r[i] = __builtin_nontemporal_load(p + i * 64 + lane);

    // ---- Phase 1: threshold scan, ballot-compacted, atomic-free --------
    // thr=2.45: count ~ Bin(8192,0.00714): E=58, sigma=7.6. Retries
    // (P~2e-4) re-scan registers. count is wave-uniform (scalar) since it
    // only accumulates popc(ballot).
    const float thrs[6] = {2.45f, 2.0f, 3.2f, 1.2f, 0.0f, -2.0f};
    bool ok = false;
    int count = 0;

    for (int ti = 0; ti < 6 && !ok; ++ti) {
        const float thr = thrs[ti];
        count = 0;
        #pragma unroll
        for (int i = 0; i < 32; ++i) {
            #pragma unroll
            for (int c = 0; c < 4; ++c) {
                const float f = r[i][c];
                const bool pred = f > thr;
                const u64 m = __ballot(pred);
                if (m) {                       // wave-uniform branch
                    if (pred) {
                        const int off =
                            count + (int)__popcll(m & ((1ull << lane) - 1ull));
                        if (off < WCAP) {
                            const int idx = (i * 64 + lane) * 4 + c;
                            cand[off] = ((u64)f2key(f) << 32) |
                                        (uint32_t)(~(uint32_t)idx);
                        }
                    }
                    count += (int)__popcll(m);
                }
            }
        }
        ok = (count >= k && count <= WCAP);
    }
    __builtin_amdgcn_wave_barrier();   // codegen fence before cross-lane reads

    // ---- Phase 2: rank-based top-k selection (wave-local) --------------
    if (ok) {
        // rank(i) = #{j : key_j > key_i}; unique keys -> unique ranks ->
        // race-free deterministic sel. cand[j] reads are same-address
        // across lanes -> LDS broadcast. 8x unroll = 8 reads in flight.
        #pragma unroll
        for (int m4 = 0; m4 < WCAP / 64; ++m4) {
            const int i = m4 * 64 + lane;
            if (i < count) {
                const u64 mykey = cand[i];
                int rank = 0;
                int j = 0;
                for (; j + 8 <= count; j += 8) {
                    const u64 c0 = cand[j + 0];
                    const u64 c1 = cand[j + 1];
                    const u64 c2 = cand[j + 2];
                    const u64 c3 = cand[j + 3];
                    const u64 c4 = cand[j + 4];
                    const u64 c5 = cand[j + 5];
                    const u64 c6 = cand[j + 6];
                    const u64 c7 = cand[j + 7];
                    rank += (c0 > mykey) + (c1 > mykey) + (c2 > mykey) +
                            (c3 > mykey) + (c4 > mykey) + (c5 > mykey) +
                            (c6 > mykey) + (c7 > mykey);
                }
                for (; j < count; ++j)
                    rank += (cand[j] > mykey) ? 1 : 0;
                if (rank < k)
                    sel[rank] = (int)(~(uint32_t)(mykey & 0xFFFFFFFFull));
            }
        }
    } else {
        // exact (slow) wave-local fallback — never triggers for normal data
        for (int t = 0; t < k; ++t) {
            u64 best = 0ull;
            #pragma unroll
            for (int i = 0; i < 32; ++i) {
                #pragma unroll
                for (int c = 0; c < 4; ++c) {
                    const int idx = (i * 64 + lane) * 4 + c;
                    bool taken = false;
                    for (int s = 0; s < t; ++s) taken |= (sel[s] == idx);
                    if (!taken) {
                        const u64 comp = ((u64)f2key(r[i][c]) << 32) |
                                         (uint32_t)(~(uint32_t)idx);
                        if (comp > best) best = comp;
                    }
                }
            }
            #pragma unroll
            for (int o = 32; o > 0; o >>= 1) {
                const u64 other = __shfl_xor(best, o, 64);
                if (other > best) best = other;
            }
            if (lane == 0)
                sel[t] = (int)(~(uint32_t)(best & 0xFFFFFFFFull));
            __builtin_amdgcn_wave_barrier();
        }
    }
    __builtin_amdgcn_wave_barrier();   // sel writes ordered before gather

    // ---- Phase 3: gather + residual ------------------------------------
    // sel[t] reads are wave-uniform -> LDS broadcast. Per selected row,
    // the wave reads one contiguous 1KB line of X (L2/L3-hot; A used NT
    // loads so X stays resident). 4 v4f accumulators -> ILP 4x4 floats.
    if (k == 32) {
        v4f a0 = {0.f, 0.f, 0.f, 0.f}, a1 = a0, a2 = a0, a3 = a0;
        #pragma unroll
        for (int t = 0; t < 32; t += 4) {
            const v4f g0 = *reinterpret_cast<const v4f*>(
                X + (size_t)sel[t + 0] * DDIM + 4 * lane);
            const v4f g1 = *reinterpret_cast<const v4f*>(
                X + (size_t)sel[t + 1] * DDIM + 4 * lane);
            const v4f g2 = *reinterpret_cast<const v4f*>(
                X + (size_t)sel[t + 2] * DDIM + 4 * lane);
            const v4f g3 = *reinterpret_cast<const v4f*>(
                X + (size_t)sel[t + 3] * DDIM + 4 * lane);
            a0 += g0; a1 += g1; a2 += g2; a3 += g3;
        }
        const v4f acc = (a0 + a1) + (a2 + a3);
        const v4f o = xres + alpha * acc;
        __builtin_nontemporal_store(
            o, reinterpret_cast<v4f*>(out + (size_t)row * DDIM + 4 * lane));
    } else {
        v4f acc = {0.f, 0.f, 0.f, 0.f};
        for (int t = 0; t < k; ++t)
            acc += *reinterpret_cast<const v4f*>(
                X + (size_t)sel[t] * DDIM + 4 * lane);
        const v4f o = xres + alpha * acc;
        __builtin_nontemporal_store(
            o, reinterpret_cast<v4f*>(out + (size_t)row * DDIM + 4 * lane));
    }
}

extern "C" void kernel_launch(void* const* d_in, const int* in_sizes, int n_in,
                              void* d_out, int out_size, void* d_ws, size_t ws_size,
                              hipStream_t stream) {
    const float* A     = (const float*)d_in[0];
    const float* X     = (const float*)d_in[1];
    const float* alpha = (const float*)d_in[2];
    const int*   k     = (const int*)d_in[3];
    float* out = (float*)d_out;

    topk_agg_wave<<<NDIM / 4, 256, 0, stream>>>(A, X, alpha, k, out);
}

// Round 10
// 67.993 us; speedup vs baseline: 2.9759x; 2.9759x over previous
//
#include <hip/hip_runtime.h>
#include <stdint.h>

#define NDIM 8192
#define DDIM 256
#define WCAP 256   // per-wave candidate capacity
#define MAXK 64

typedef float v4f __attribute__((ext_vector_type(4)));
typedef unsigned long long u64;

// Map float bits to an unsigned key with the same total order.
__device__ inline uint32_t f2key(float f) {
    uint32_t u = __float_as_uint(f);
    return (u & 0x80000000u) ? ~u : (u | 0x80000000u);
}

// One WAVE per row, zero block barriers. Row is consumed in 4 chunks of
// 8 float4 per lane, double-buffered in registers: chunk j+1's NT loads are
// in flight while chunk j is ballot-compacted. With no s_barrier there is no
// forced vmcnt(0) drain, and waves drift out of phase so one wave's
// select/gather tail overlaps other waves' HBM streaming (convoy-breaker).
__global__ __launch_bounds__(256) void topk_agg_wave(
    const float* __restrict__ A, const float* __restrict__ X,
    const float* __restrict__ alpha_p, const int* __restrict__ k_p,
    float* __restrict__ out)
{
    const int tid  = threadIdx.x;
    const int lane = tid & 63;
    const int wid  = tid >> 6;
    const int row  = blockIdx.x * 4 + wid;

    // Wave-private LDS regions — disjoint per wave, never cross-wave shared.
    __shared__ u64 cand_s[4][WCAP];
    __shared__ int sel_s[4][MAXK];
    u64* cand = cand_s[wid];
    int* sel  = sel_s[wid];

    int k = *k_p;
    if (k > MAXK) k = MAXK;            // defensive clamp (k==32 here)
    const float alpha = *alpha_p;

    // Residual: lane owns cols 4*lane..4*lane+3 (coalesced float4).
    const v4f xres =
        *reinterpret_cast<const v4f*>(X + (size_t)row * DDIM + 4 * lane);

    const v4f* p = reinterpret_cast<const v4f*>(A + (size_t)row * NDIM);
    const u64 lmask = (1ull << lane) - 1ull;

    int count = 0;

    // Chunked double-buffer: 2 x 8 v4f = 64 VGPR live; all indexing is
    // compile-time (fully unrolled) so buffers stay in VGPRs (R9 lesson:
    // no launch-bounds min-waves -> allocator must not spill).
    v4f bufA[8], bufB[8];

    auto prefetch = [&](v4f (&buf)[8], int chunk) {
        #pragma unroll
        for (int i = 0; i < 8; ++i)
            buf[i] = __builtin_nontemporal_load(p + (chunk * 8 + i) * 64 + lane);
    };
    // Ballot-compact chunk into wave-private cand[]; count stays
    // wave-uniform (scalar) since it only accumulates popc(ballot).
    auto compact = [&](v4f (&buf)[8], int chunk, float thr) {
        #pragma unroll
        for (int i = 0; i < 8; ++i) {
            #pragma unroll
            for (int c = 0; c < 4; ++c) {
                const float f = buf[i][c];
                const bool pred = f > thr;
                const u64 m = __ballot(pred);
                if (pred) {
                    const int off = count + (int)__popcll(m & lmask);
                    if (off < WCAP) {
                        const int idx = ((chunk * 8 + i) * 64 + lane) * 4 + c;
                        cand[off] = ((u64)f2key(f) << 32) |
                                    (uint32_t)(~(uint32_t)idx);
                    }
                }
                count += (int)__popcll(m);
            }
        }
    };

    // Fast pass: thr=2.45 -> count ~ Bin(8192,0.00714): E=58, sigma=7.6.
    const float thrs[6] = {2.45f, 2.0f, 3.2f, 1.2f, 0.0f, -2.0f};
    prefetch(bufA, 0);
    prefetch(bufB, 1);
    compact(bufA, 0, thrs[0]);
    prefetch(bufA, 2);
    compact(bufB, 1, thrs[0]);
    prefetch(bufB, 3);
    compact(bufA, 2, thrs[0]);
    compact(bufB, 3, thrs[0]);

    bool ok = (count >= k && count <= WCAP);

    // Rare retries (P ~ 2e-4 per row): simple re-read from global.
    for (int ti = 1; ti < 6 && !ok; ++ti) {
        const float thr = thrs[ti];
        count = 0;
        for (int q = 0; q < 32; ++q) {
            const v4f v = p[q * 64 + lane];
            #pragma unroll
            for (int c = 0; c < 4; ++c) {
                const float f = v[c];
                const bool pred = f > thr;
                const u64 m = __ballot(pred);
                if (pred) {
                    const int off = count + (int)__popcll(m & lmask);
                    if (off < WCAP) {
                        const int idx = (q * 64 + lane) * 4 + c;
                        cand[off] = ((u64)f2key(f) << 32) |
                                    (uint32_t)(~(uint32_t)idx);
                    }
                }
                count += (int)__popcll(m);
            }
        }
        ok = (count >= k && count <= WCAP);
    }
    __builtin_amdgcn_wave_barrier();   // codegen fence before cross-lane reads

    // ---- Phase 2: rank-based top-k selection (wave-local, R9-proven) ----
    if (ok) {
        // rank(i) = #{j : key_j > key_i}; unique keys -> unique ranks ->
        // race-free deterministic sel. cand[j] reads are same-address
        // across lanes -> LDS broadcast. 8x unroll = 8 reads in flight.
        #pragma unroll
        for (int m4 = 0; m4 < WCAP / 64; ++m4) {
            const int i = m4 * 64 + lane;
            if (i < count) {
                const u64 mykey = cand[i];
                int rank = 0;
                int j = 0;
                for (; j + 8 <= count; j += 8) {
                    const u64 c0 = cand[j + 0];
                    const u64 c1 = cand[j + 1];
                    const u64 c2 = cand[j + 2];
                    const u64 c3 = cand[j + 3];
                    const u64 c4 = cand[j + 4];
                    const u64 c5 = cand[j + 5];
                    const u64 c6 = cand[j + 6];
                    const u64 c7 = cand[j + 7];
                    rank += (c0 > mykey) + (c1 > mykey) + (c2 > mykey) +
                            (c3 > mykey) + (c4 > mykey) + (c5 > mykey) +
                            (c6 > mykey) + (c7 > mykey);
                }
                for (; j < count; ++j)
                    rank += (cand[j] > mykey) ? 1 : 0;
                if (rank < k)
                    sel[rank] = (int)(~(uint32_t)(mykey & 0xFFFFFFFFull));
            }
        }
    } else {
        // exact (slow) wave-local fallback — never triggers for normal
        // data; re-reads the row (L2-warm after retries).
        for (int t = 0; t < k; ++t) {
            u64 best = 0ull;
            for (int q = 0; q < 32; ++q) {
                const v4f v = p[q * 64 + lane];
                #pragma unroll
                for (int c = 0; c < 4; ++c) {
                    const int idx = (q * 64 + lane) * 4 + c;
                    bool taken = false;
                    for (int s = 0; s < t; ++s) taken |= (sel[s] == idx);
                    if (!taken) {
                        const u64 comp = ((u64)f2key(v[c]) << 32) |
                                         (uint32_t)(~(uint32_t)idx);
                        if (comp > best) best = comp;
                    }
                }
            }
            #pragma unroll
            for (int o = 32; o > 0; o >>= 1) {
                const u64 other = __shfl_xor(best, o, 64);
                if (other > best) best = other;
            }
            if (lane == 0)
                sel[t] = (int)(~(uint32_t)(best & 0xFFFFFFFFull));
            __builtin_amdgcn_wave_barrier();
        }
    }
    __builtin_amdgcn_wave_barrier();   // sel writes ordered before gather

    // ---- Phase 3: gather + residual (wave-local, R9-proven) -------------
    // sel[t] reads are wave-uniform -> LDS broadcast. Per selected row the
    // wave reads one contiguous 1KB line of X (L2/L3-hot; A used NT loads
    // so X stays resident). 4 v4f accumulators -> 4 loads in flight.
    if (k == 32) {
        v4f a0 = {0.f, 0.f, 0.f, 0.f}, a1 = a0, a2 = a0, a3 = a0;
        #pragma unroll
        for (int t = 0; t < 32; t += 4) {
            const v4f g0 = *reinterpret_cast<const v4f*>(
                X + (size_t)sel[t + 0] * DDIM + 4 * lane);
            const v4f g1 = *reinterpret_cast<const v4f*>(
                X + (size_t)sel[t + 1] * DDIM + 4 * lane);
            const v4f g2 = *reinterpret_cast<const v4f*>(
                X + (size_t)sel[t + 2] * DDIM + 4 * lane);
            const v4f g3 = *reinterpret_cast<const v4f*>(
                X + (size_t)sel[t + 3] * DDIM + 4 * lane);
            a0 += g0; a1 += g1; a2 += g2; a3 += g3;
        }
        const v4f acc = (a0 + a1) + (a2 + a3);
        const v4f o = xres + alpha * acc;
        __builtin_nontemporal_store(
            o, reinterpret_cast<v4f*>(out + (size_t)row * DDIM + 4 * lane));
    } else {
        v4f acc = {0.f, 0.f, 0.f, 0.f};
        for (int t = 0; t < k; ++t)
            acc += *reinterpret_cast<const v4f*>(
                X + (size_t)sel[t] * DDIM + 4 * lane);
        const v4f o = xres + alpha * acc;
        __builtin_nontemporal_store(
            o, reinterpret_cast<v4f*>(out + (size_t)row * DDIM + 4 * lane));
    }
}

extern "C" void kernel_launch(void* const* d_in, const int* in_sizes, int n_in,
                              void* d_out, int out_size, void* d_ws, size_t ws_size,
                              hipStream_t stream) {
    const float* A     = (const float*)d_in[0];
    const float* X     = (const float*)d_in[1];
    const float* alpha = (const float*)d_in[2];
    const int*   k     = (const int*)d_in[3];
    float* out = (float*)d_out;

    topk_agg_wave<<<NDIM / 4, 256, 0, stream>>>(A, X, alpha, k, out);
}